// Round 2
// baseline (615.168 us; speedup 1.0000x reference)
//
#include <hip/hip_runtime.h>

typedef __bf16 bf16_t;
typedef __bf16 bf16x8 __attribute__((ext_vector_type(8)));
typedef __bf16 bf16x4 __attribute__((ext_vector_type(4)));
typedef float f32x4 __attribute__((ext_vector_type(4)));

#define NB 8
#define SQ 2048
#define SK 2048
#define DD 512

#define BM 128
#define BN 128
#define BK 32
#define LDK 40  // padded LDS row stride in bf16 (80 B = 5*16 B: keeps b128 alignment)

// ------------------------------------------------- logits = (2 q.k - k^2)/T
// bf16 hi/lo split GEMM: q.k = qh*kh + qh*kl + ql*kh (fp32 accum), ~2^-17 rel.
// q^2 row term is softmax-invariant and dropped. k^2 computed in-kernel from
// the staged K tiles (no workspace needed).
__global__ __launch_bounds__(256, 2) void logits_kernel(
    const float* __restrict__ Q, const float* __restrict__ K,
    const float* __restrict__ tempP, float* __restrict__ logits) {
  __shared__ bf16_t qh[BM][LDK], ql[BM][LDK], kh[BN][LDK], kl[BN][LDK];
  __shared__ float ksred[BN][8];
  const int b = blockIdx.z;
  const int m0 = blockIdx.y * BM;
  const int n0 = blockIdx.x * BN;
  const int tid = threadIdx.x;
  const int lane = tid & 63;
  const int wave = tid >> 6;
  const int wm = (wave >> 1) * 64;
  const int wn = (wave & 1) * 64;
  const int lrow = lane & 15;
  const int quad = lane >> 4;

  const float* Qb = Q + (size_t)b * SQ * DD;
  const float* Kb = K + (size_t)b * SK * DD;

  f32x4 acc[4][4];
#pragma unroll
  for (int i = 0; i < 4; i++)
#pragma unroll
    for (int j = 0; j < 4; j++) acc[i][j] = (f32x4){0.f, 0.f, 0.f, 0.f};

  float kss[4] = {0.f, 0.f, 0.f, 0.f};

  const int srow = tid >> 3;        // 0..31
  const int scol = (tid & 7) * 4;   // 0,4,...,28

  for (int k0 = 0; k0 < DD; k0 += BK) {
    __syncthreads();
#pragma unroll
    for (int i = 0; i < 4; i++) {
      const int r = srow + i * 32;
      float4 qv = *(const float4*)(Qb + (size_t)(m0 + r) * DD + k0 + scol);
      float4 kv = *(const float4*)(Kb + (size_t)(n0 + r) * DD + k0 + scol);
      bf16_t qh0 = (bf16_t)qv.x, qh1 = (bf16_t)qv.y, qh2 = (bf16_t)qv.z, qh3 = (bf16_t)qv.w;
      bf16x4 qhv = {qh0, qh1, qh2, qh3};
      bf16x4 qlv = {(bf16_t)(qv.x - (float)qh0), (bf16_t)(qv.y - (float)qh1),
                    (bf16_t)(qv.z - (float)qh2), (bf16_t)(qv.w - (float)qh3)};
      bf16_t kh0 = (bf16_t)kv.x, kh1 = (bf16_t)kv.y, kh2 = (bf16_t)kv.z, kh3 = (bf16_t)kv.w;
      bf16x4 khv = {kh0, kh1, kh2, kh3};
      bf16x4 klv = {(bf16_t)(kv.x - (float)kh0), (bf16_t)(kv.y - (float)kh1),
                    (bf16_t)(kv.z - (float)kh2), (bf16_t)(kv.w - (float)kh3)};
      *(bf16x4*)&qh[r][scol] = qhv;
      *(bf16x4*)&ql[r][scol] = qlv;
      *(bf16x4*)&kh[r][scol] = khv;
      *(bf16x4*)&kl[r][scol] = klv;
      kss[i] = fmaf(kv.x, kv.x, kss[i]);
      kss[i] = fmaf(kv.y, kv.y, kss[i]);
      kss[i] = fmaf(kv.z, kv.z, kss[i]);
      kss[i] = fmaf(kv.w, kv.w, kss[i]);
    }
    __syncthreads();

    bf16x8 ah[4], al[4], bh[4], bl[4];
#pragma unroll
    for (int mi = 0; mi < 4; mi++) {
      ah[mi] = *(const bf16x8*)&qh[wm + mi * 16 + lrow][quad * 8];
      al[mi] = *(const bf16x8*)&ql[wm + mi * 16 + lrow][quad * 8];
    }
#pragma unroll
    for (int ni = 0; ni < 4; ni++) {
      bh[ni] = *(const bf16x8*)&kh[wn + ni * 16 + lrow][quad * 8];
      bl[ni] = *(const bf16x8*)&kl[wn + ni * 16 + lrow][quad * 8];
    }
#pragma unroll
    for (int mi = 0; mi < 4; mi++)
#pragma unroll
      for (int ni = 0; ni < 4; ni++) {
        acc[mi][ni] = __builtin_amdgcn_mfma_f32_16x16x32_bf16(ah[mi], bh[ni], acc[mi][ni], 0, 0, 0);
        acc[mi][ni] = __builtin_amdgcn_mfma_f32_16x16x32_bf16(ah[mi], bl[ni], acc[mi][ni], 0, 0, 0);
        acc[mi][ni] = __builtin_amdgcn_mfma_f32_16x16x32_bf16(al[mi], bh[ni], acc[mi][ni], 0, 0, 0);
      }
  }

  // k^2 reduction: each thread owns rows {srow+32i}, column-group tid&7
#pragma unroll
  for (int i = 0; i < 4; i++) ksred[srow + i * 32][tid & 7] = kss[i];
  __syncthreads();

  const float invT = 1.0f / tempP[0];
  float* Lb = logits + (size_t)b * SQ * SK;
#pragma unroll
  for (int ni = 0; ni < 4; ni++) {
    const int nl = wn + ni * 16 + lrow;
    const int n = n0 + nl;
    const float* kr = ksred[nl];
    const float ks = ((kr[0] + kr[1]) + (kr[2] + kr[3])) +
                     ((kr[4] + kr[5]) + (kr[6] + kr[7]));
#pragma unroll
    for (int mi = 0; mi < 4; mi++) {
      const int mbase = m0 + wm + mi * 16 + quad * 4;
#pragma unroll
      for (int r = 0; r < 4; r++) {
        float s = (2.0f * acc[mi][ni][r] - ks) * invT;
        Lb[(size_t)(mbase + r) * SK + n] = s;
      }
    }
  }
}

// ----------------------------------------------- row softmax (in place)
__global__ __launch_bounds__(256) void softmax_kernel(float* __restrict__ L) {
  float* p = L + (size_t)blockIdx.x * SK;
  const int tid = threadIdx.x;
  const int wave = tid >> 6, lane = tid & 63;

  float4 a = *(const float4*)(p + tid * 4);
  float4 bv = *(const float4*)(p + 1024 + tid * 4);

  float m = fmaxf(fmaxf(fmaxf(a.x, a.y), fmaxf(a.z, a.w)),
                  fmaxf(fmaxf(bv.x, bv.y), fmaxf(bv.z, bv.w)));
#pragma unroll
  for (int off = 32; off; off >>= 1) m = fmaxf(m, __shfl_xor(m, off));
  __shared__ float redm[4];
  if (lane == 0) redm[wave] = m;
  __syncthreads();
  m = fmaxf(fmaxf(redm[0], redm[1]), fmaxf(redm[2], redm[3]));

  float e[8];
  e[0] = __expf(a.x - m);  e[1] = __expf(a.y - m);
  e[2] = __expf(a.z - m);  e[3] = __expf(a.w - m);
  e[4] = __expf(bv.x - m); e[5] = __expf(bv.y - m);
  e[6] = __expf(bv.z - m); e[7] = __expf(bv.w - m);
  float s = ((e[0] + e[1]) + (e[2] + e[3])) + ((e[4] + e[5]) + (e[6] + e[7]));
#pragma unroll
  for (int off = 32; off; off >>= 1) s += __shfl_xor(s, off);
  __shared__ float reds[4];
  if (lane == 0) reds[wave] = s;
  __syncthreads();
  s = (reds[0] + reds[1]) + (reds[2] + reds[3]);

  const float inv = 1.0f / s;
  float4 oa = {e[0] * inv, e[1] * inv, e[2] * inv, e[3] * inv};
  float4 ob = {e[4] * inv, e[5] * inv, e[6] * inv, e[7] * inv};
  *(float4*)(p + tid * 4) = oa;
  *(float4*)(p + 1024 + tid * 4) = ob;
}

// ------------------------------------------------- O = W @ V (bf16 MFMA)
__global__ __launch_bounds__(256, 2) void pv_kernel(const float* __restrict__ W,
                                                    const float* __restrict__ V,
                                                    float* __restrict__ O) {
  __shared__ bf16_t wt[BM][LDK];  // [m][k]
  __shared__ bf16_t vt[BN][LDK];  // [d][k]
  const int b = blockIdx.z;
  const int m0 = blockIdx.y * BM;
  const int d0 = blockIdx.x * BN;
  const int tid = threadIdx.x;
  const int lane = tid & 63;
  const int wave = tid >> 6;
  const int wm = (wave >> 1) * 64;
  const int wn = (wave & 1) * 64;
  const int lrow = lane & 15;
  const int quad = lane >> 4;

  const float* Wb = W + (size_t)b * SQ * SK;
  const float* Vb = V + (size_t)b * SK * DD;

  f32x4 acc[4][4];
#pragma unroll
  for (int i = 0; i < 4; i++)
#pragma unroll
    for (int j = 0; j < 4; j++) acc[i][j] = (f32x4){0.f, 0.f, 0.f, 0.f};

  const int srow = tid >> 3;
  const int scol = (tid & 7) * 4;

  for (int k0 = 0; k0 < SK; k0 += BK) {
    __syncthreads();
#pragma unroll
    for (int i = 0; i < 4; i++) {
      const int r = srow + i * 32;
      float4 w = *(const float4*)(Wb + (size_t)(m0 + r) * SK + k0 + scol);
      bf16x4 w4 = {(bf16_t)w.x, (bf16_t)w.y, (bf16_t)w.z, (bf16_t)w.w};
      *(bf16x4*)&wt[r][scol] = w4;
    }
    {
      const int kk = tid >> 5;         // 0..7
      const int dd = (tid & 31) * 4;   // 0..124
#pragma unroll
      for (int i = 0; i < 4; i++) {
        const int k = kk + i * 8;
        float4 v = *(const float4*)(Vb + (size_t)(k0 + k) * DD + d0 + dd);
        vt[dd + 0][k] = (bf16_t)v.x;
        vt[dd + 1][k] = (bf16_t)v.y;
        vt[dd + 2][k] = (bf16_t)v.z;
        vt[dd + 3][k] = (bf16_t)v.w;
      }
    }
    __syncthreads();

    bf16x8 a[4], bb[4];
#pragma unroll
    for (int mi = 0; mi < 4; mi++)
      a[mi] = *(const bf16x8*)&wt[wm + mi * 16 + lrow][quad * 8];
#pragma unroll
    for (int ni = 0; ni < 4; ni++)
      bb[ni] = *(const bf16x8*)&vt[wn + ni * 16 + lrow][quad * 8];
#pragma unroll
    for (int mi = 0; mi < 4; mi++)
#pragma unroll
      for (int ni = 0; ni < 4; ni++)
        acc[mi][ni] = __builtin_amdgcn_mfma_f32_16x16x32_bf16(a[mi], bb[ni], acc[mi][ni], 0, 0, 0);
  }

  float* Ob = O + (size_t)b * SQ * DD;
#pragma unroll
  for (int ni = 0; ni < 4; ni++) {
    const int d = d0 + wn + ni * 16 + lrow;
#pragma unroll
    for (int mi = 0; mi < 4; mi++) {
      const int mbase = m0 + wm + mi * 16 + quad * 4;
#pragma unroll
      for (int r = 0; r < 4; r++) {
        Ob[(size_t)(mbase + r) * DD + d] = acc[mi][ni][r];
      }
    }
  }
}

extern "C" void kernel_launch(void* const* d_in, const int* in_sizes, int n_in,
                              void* d_out, int out_size, void* d_ws, size_t ws_size,
                              hipStream_t stream) {
  const float* Q = (const float*)d_in[0];
  const float* K = (const float*)d_in[1];
  const float* V = (const float*)d_in[2];
  const float* T = (const float*)d_in[3];

  float* outv = (float*)d_out;                          // [8,2048,512]
  float* logits = outv + (size_t)NB * SQ * DD;          // [8,2048,2048] (weights region)

  // 1) logits GEMM (bf16 hi/lo split, fp32 accum, in-kernel k^2)
  logits_kernel<<<dim3(SK / BN, SQ / BM, NB), 256, 0, stream>>>(Q, K, T, logits);

  // 2) softmax normalize in place -> attention_weights
  softmax_kernel<<<NB * SQ, 256, 0, stream>>>(logits);

  // 3) attended = W @ V
  pv_kernel<<<dim3(DD / BN, SQ / BM, NB), 256, 0, stream>>>(logits, V, outv);
}

// Round 4
// 501.424 us; speedup vs baseline: 1.2268x; 1.2268x over previous
//
#include <hip/hip_runtime.h>

typedef __bf16 bf16_t;
typedef __bf16 bf16x8 __attribute__((ext_vector_type(8)));
typedef __bf16 bf16x4 __attribute__((ext_vector_type(4)));
typedef float f32x4 __attribute__((ext_vector_type(4)));

#define NB 8
#define SQ 2048
#define SK 2048
#define DD 512

#define BM 128
#define BN 128
#define BK 32
#define LDK 40   // padded LDS row stride (80 B, 16B-aligned rows for b128)

// ------------------------------------------------- logits = (2 q.k - k^2)/T
// bf16 hi/lo split GEMM: q.k = qh*kh + qh*kl + ql*kh (fp32 accum), ~2^-17 rel.
// q^2 row term is softmax-invariant and dropped. k^2 computed in-kernel.
// Register prefetch: next tile's global loads issue right after the staging
// barrier so their ~900-cyc latency hides under the MFMA phase.
__global__ __launch_bounds__(256, 2) void logits_kernel(
    const float* __restrict__ Q, const float* __restrict__ K,
    const float* __restrict__ tempP, float* __restrict__ logits) {
  __shared__ bf16_t qh[BM][LDK], ql[BM][LDK], kh[BN][LDK], kl[BN][LDK];
  __shared__ float ksred[BN][8];
  const int b = blockIdx.z;
  const int m0 = blockIdx.y * BM;
  const int n0 = blockIdx.x * BN;
  const int tid = threadIdx.x;
  const int lane = tid & 63;
  const int wave = tid >> 6;
  const int wm = (wave >> 1) * 64;
  const int wn = (wave & 1) * 64;
  const int lrow = lane & 15;
  const int quad = lane >> 4;

  const float* Qb = Q + (size_t)b * SQ * DD;
  const float* Kb = K + (size_t)b * SK * DD;

  const int srow = tid >> 3;        // 0..31
  const int scol = (tid & 7) * 4;   // 0,4,...,28

  const float* qbase = Qb + (size_t)(m0 + srow) * DD + scol;
  const float* kbase = Kb + (size_t)(n0 + srow) * DD + scol;

  f32x4 acc[4][4];
#pragma unroll
  for (int i = 0; i < 4; i++)
#pragma unroll
    for (int j = 0; j < 4; j++) acc[i][j] = (f32x4){0.f, 0.f, 0.f, 0.f};

  float kss[4] = {0.f, 0.f, 0.f, 0.f};

  float4 pq[4], pk[4];
#pragma unroll
  for (int i = 0; i < 4; i++) {
    pq[i] = *(const float4*)(qbase + (size_t)i * 32 * DD);
    pk[i] = *(const float4*)(kbase + (size_t)i * 32 * DD);
  }

  for (int k0 = 0; k0 < DD; k0 += BK) {
    __syncthreads();  // previous iteration's LDS reads complete
    // ---- convert + LDS store (consumes prefetch regs)
#pragma unroll
    for (int i = 0; i < 4; i++) {
      const int r = srow + i * 32;
      float4 qv = pq[i], kv = pk[i];
      bf16_t q0 = (bf16_t)qv.x, q1 = (bf16_t)qv.y, q2 = (bf16_t)qv.z, q3 = (bf16_t)qv.w;
      bf16x4 qhv = {q0, q1, q2, q3};
      bf16x4 qlv = {(bf16_t)(qv.x - (float)q0), (bf16_t)(qv.y - (float)q1),
                    (bf16_t)(qv.z - (float)q2), (bf16_t)(qv.w - (float)q3)};
      bf16_t c0 = (bf16_t)kv.x, c1 = (bf16_t)kv.y, c2 = (bf16_t)kv.z, c3 = (bf16_t)kv.w;
      bf16x4 khv = {c0, c1, c2, c3};
      bf16x4 klv = {(bf16_t)(kv.x - (float)c0), (bf16_t)(kv.y - (float)c1),
                    (bf16_t)(kv.z - (float)c2), (bf16_t)(kv.w - (float)c3)};
      *(bf16x4*)&qh[r][scol] = qhv;
      *(bf16x4*)&ql[r][scol] = qlv;
      *(bf16x4*)&kh[r][scol] = khv;
      *(bf16x4*)&kl[r][scol] = klv;
      kss[i] = fmaf(kv.x, kv.x, kss[i]);
      kss[i] = fmaf(kv.y, kv.y, kss[i]);
      kss[i] = fmaf(kv.z, kv.z, kss[i]);
      kss[i] = fmaf(kv.w, kv.w, kss[i]);
    }
    __syncthreads();

    // ---- prefetch next tile (global reads only; hide under MFMA)
    if (k0 + BK < DD) {
#pragma unroll
      for (int i = 0; i < 4; i++) {
        pq[i] = *(const float4*)(qbase + (size_t)i * 32 * DD + (k0 + BK));
        pk[i] = *(const float4*)(kbase + (size_t)i * 32 * DD + (k0 + BK));
      }
    }

    // ---- MFMA phase
    bf16x8 bh[4], bl[4];
#pragma unroll
    for (int ni = 0; ni < 4; ni++) {
      bh[ni] = *(const bf16x8*)&kh[wn + ni * 16 + lrow][quad * 8];
      bl[ni] = *(const bf16x8*)&kl[wn + ni * 16 + lrow][quad * 8];
    }
#pragma unroll
    for (int mi = 0; mi < 4; mi++) {
      bf16x8 ah = *(const bf16x8*)&qh[wm + mi * 16 + lrow][quad * 8];
      bf16x8 al = *(const bf16x8*)&ql[wm + mi * 16 + lrow][quad * 8];
#pragma unroll
      for (int ni = 0; ni < 4; ni++) {
        acc[mi][ni] = __builtin_amdgcn_mfma_f32_16x16x32_bf16(ah, bh[ni], acc[mi][ni], 0, 0, 0);
        acc[mi][ni] = __builtin_amdgcn_mfma_f32_16x16x32_bf16(ah, bl[ni], acc[mi][ni], 0, 0, 0);
        acc[mi][ni] = __builtin_amdgcn_mfma_f32_16x16x32_bf16(al, bh[ni], acc[mi][ni], 0, 0, 0);
      }
    }
  }

  // ---- k^2 reduction (separate LDS buffer; R2-proven)
#pragma unroll
  for (int i = 0; i < 4; i++) ksred[srow + i * 32][tid & 7] = kss[i];
  __syncthreads();

  const float invT = 1.0f / tempP[0];
  float* Lb = logits + (size_t)b * SQ * SK;
#pragma unroll
  for (int ni = 0; ni < 4; ni++) {
    const int nl = wn + ni * 16 + lrow;
    const int n = n0 + nl;
    const float* kr = ksred[nl];
    const float ks = ((kr[0] + kr[1]) + (kr[2] + kr[3])) +
                     ((kr[4] + kr[5]) + (kr[6] + kr[7]));
#pragma unroll
    for (int mi = 0; mi < 4; mi++) {
      const int mbase = m0 + wm + mi * 16 + quad * 4;
#pragma unroll
      for (int r = 0; r < 4; r++) {
        float s = (2.0f * acc[mi][ni][r] - ks) * invT;
        Lb[(size_t)(mbase + r) * SK + n] = s;
      }
    }
  }
}

// ----------------------------------------------- row softmax (in place)
__global__ __launch_bounds__(256) void softmax_kernel(float* __restrict__ L) {
  float* p = L + (size_t)blockIdx.x * SK;
  const int tid = threadIdx.x;
  const int wave = tid >> 6, lane = tid & 63;

  float4 a = *(const float4*)(p + tid * 4);
  float4 bv = *(const float4*)(p + 1024 + tid * 4);

  float m = fmaxf(fmaxf(fmaxf(a.x, a.y), fmaxf(a.z, a.w)),
                  fmaxf(fmaxf(bv.x, bv.y), fmaxf(bv.z, bv.w)));
#pragma unroll
  for (int off = 32; off; off >>= 1) m = fmaxf(m, __shfl_xor(m, off));
  __shared__ float redm[4];
  if (lane == 0) redm[wave] = m;
  __syncthreads();
  m = fmaxf(fmaxf(redm[0], redm[1]), fmaxf(redm[2], redm[3]));

  float e[8];
  e[0] = __expf(a.x - m);  e[1] = __expf(a.y - m);
  e[2] = __expf(a.z - m);  e[3] = __expf(a.w - m);
  e[4] = __expf(bv.x - m); e[5] = __expf(bv.y - m);
  e[6] = __expf(bv.z - m); e[7] = __expf(bv.w - m);
  float s = ((e[0] + e[1]) + (e[2] + e[3])) + ((e[4] + e[5]) + (e[6] + e[7]));
#pragma unroll
  for (int off = 32; off; off >>= 1) s += __shfl_xor(s, off);
  __shared__ float reds[4];
  if (lane == 0) reds[wave] = s;
  __syncthreads();
  s = (reds[0] + reds[1]) + (reds[2] + reds[3]);

  const float inv = 1.0f / s;
  float4 oa = {e[0] * inv, e[1] * inv, e[2] * inv, e[3] * inv};
  float4 ob = {e[4] * inv, e[5] * inv, e[6] * inv, e[7] * inv};
  *(float4*)(p + tid * 4) = oa;
  *(float4*)(p + 1024 + tid * 4) = ob;
}

// ------------------------------------------------- O = W @ V (bf16 MFMA)
__global__ __launch_bounds__(256, 2) void pv_kernel(const float* __restrict__ W,
                                                    const float* __restrict__ V,
                                                    float* __restrict__ O) {
  __shared__ bf16_t wt[BM][LDK];  // [m][k]
  __shared__ bf16_t vt[BN][LDK];  // [d][k]
  const int b = blockIdx.z;
  const int m0 = blockIdx.y * BM;
  const int d0 = blockIdx.x * BN;
  const int tid = threadIdx.x;
  const int lane = tid & 63;
  const int wave = tid >> 6;
  const int wm = (wave >> 1) * 64;
  const int wn = (wave & 1) * 64;
  const int lrow = lane & 15;
  const int quad = lane >> 4;

  const float* Wb = W + (size_t)b * SQ * SK;
  const float* Vb = V + (size_t)b * SK * DD;

  const int srow = tid >> 3;
  const int scol = (tid & 7) * 4;
  const int kk = tid >> 5;          // 0..7
  const int dd4 = (tid & 31) * 4;   // 0..124

  const float* wbase = Wb + (size_t)(m0 + srow) * SK + scol;
  const float* vbase = Vb + (size_t)kk * DD + d0 + dd4;

  f32x4 acc[4][4];
#pragma unroll
  for (int i = 0; i < 4; i++)
#pragma unroll
    for (int j = 0; j < 4; j++) acc[i][j] = (f32x4){0.f, 0.f, 0.f, 0.f};

  float4 pw[4], pvv[4];
#pragma unroll
  for (int i = 0; i < 4; i++) {
    pw[i] = *(const float4*)(wbase + (size_t)i * 32 * SK);
    pvv[i] = *(const float4*)(vbase + (size_t)i * 8 * DD);
  }

  for (int k0 = 0; k0 < SK; k0 += BK) {
    __syncthreads();  // previous iteration's LDS reads complete
    // ---- convert + LDS store
#pragma unroll
    for (int i = 0; i < 4; i++) {
      float4 w = pw[i];
      bf16x4 w4 = {(bf16_t)w.x, (bf16_t)w.y, (bf16_t)w.z, (bf16_t)w.w};
      *(bf16x4*)&wt[srow + i * 32][scol] = w4;
      float4 v = pvv[i];
      const int k = kk + i * 8;
      vt[dd4 + 0][k] = (bf16_t)v.x;
      vt[dd4 + 1][k] = (bf16_t)v.y;
      vt[dd4 + 2][k] = (bf16_t)v.z;
      vt[dd4 + 3][k] = (bf16_t)v.w;
    }
    __syncthreads();

    // ---- prefetch next tile (global reads only)
    if (k0 + BK < SK) {
#pragma unroll
      for (int i = 0; i < 4; i++) {
        pw[i] = *(const float4*)(wbase + (size_t)i * 32 * SK + (k0 + BK));
        pvv[i] = *(const float4*)(vbase + (size_t)(k0 + BK + i * 8) * DD);
      }
    }

    // ---- MFMA phase
    bf16x8 a[4], bb[4];
#pragma unroll
    for (int mi = 0; mi < 4; mi++)
      a[mi] = *(const bf16x8*)&wt[wm + mi * 16 + lrow][quad * 8];
#pragma unroll
    for (int ni = 0; ni < 4; ni++)
      bb[ni] = *(const bf16x8*)&vt[wn + ni * 16 + lrow][quad * 8];
#pragma unroll
    for (int mi = 0; mi < 4; mi++)
#pragma unroll
      for (int ni = 0; ni < 4; ni++)
        acc[mi][ni] = __builtin_amdgcn_mfma_f32_16x16x32_bf16(a[mi], bb[ni], acc[mi][ni], 0, 0, 0);
  }

  float* Ob = O + (size_t)b * SQ * DD;
#pragma unroll
  for (int ni = 0; ni < 4; ni++) {
    const int d = d0 + wn + ni * 16 + lrow;
#pragma unroll
    for (int mi = 0; mi < 4; mi++) {
      const int mbase = m0 + wm + mi * 16 + quad * 4;
#pragma unroll
      for (int r = 0; r < 4; r++) {
        Ob[(size_t)(mbase + r) * DD + d] = acc[mi][ni][r];
      }
    }
  }
}

extern "C" void kernel_launch(void* const* d_in, const int* in_sizes, int n_in,
                              void* d_out, int out_size, void* d_ws, size_t ws_size,
                              hipStream_t stream) {
  const float* Q = (const float*)d_in[0];
  const float* K = (const float*)d_in[1];
  const float* V = (const float*)d_in[2];
  const float* T = (const float*)d_in[3];

  float* outv = (float*)d_out;                          // [8,2048,512]
  float* logits = outv + (size_t)NB * SQ * DD;          // [8,2048,2048] (weights region)

  logits_kernel<<<dim3(SK / BN, SQ / BM, NB), 256, 0, stream>>>(Q, K, T, logits);
  softmax_kernel<<<NB * SQ, 256, 0, stream>>>(logits);
  pv_kernel<<<dim3(DD / BN, SQ / BM, NB), 256, 0, stream>>>(logits, V, outv);
}

// Round 5
// 459.292 us; speedup vs baseline: 1.3394x; 1.0917x over previous
//
#include <hip/hip_runtime.h>

typedef __bf16 bf16_t;
typedef __bf16 bf16x8 __attribute__((ext_vector_type(8)));
typedef __bf16 bf16x4 __attribute__((ext_vector_type(4)));
typedef __bf16 bf16x2 __attribute__((ext_vector_type(2)));
typedef float f32x4 __attribute__((ext_vector_type(4)));

#define NB 8
#define SQ 2048
#define SK 2048
#define DD 512

#define BM 128
#define BN 128
#define BK 32
#define LDK 40   // padded LDS row stride (80 B, 16B-aligned rows for b128)

// ------------------------------------------------- logits = (2 q.k - k^2)/T
// bf16 hi/lo split GEMM: q.k = qh*kh + qh*kl + ql*kh (fp32 accum), ~2^-17 rel.
// q^2 row term is softmax-invariant and dropped. k^2 computed in-kernel.
// Register prefetch: next tile's global loads issue right after the staging
// barrier so their ~900-cyc latency hides under the MFMA phase.
__global__ __launch_bounds__(256, 2) void logits_kernel(
    const float* __restrict__ Q, const float* __restrict__ K,
    const float* __restrict__ tempP, float* __restrict__ logits) {
  __shared__ bf16_t qh[BM][LDK], ql[BM][LDK], kh[BN][LDK], kl[BN][LDK];
  __shared__ float ksred[BN][8];
  const int b = blockIdx.z;
  const int m0 = blockIdx.y * BM;
  const int n0 = blockIdx.x * BN;
  const int tid = threadIdx.x;
  const int lane = tid & 63;
  const int wave = tid >> 6;
  const int wm = (wave >> 1) * 64;
  const int wn = (wave & 1) * 64;
  const int lrow = lane & 15;
  const int quad = lane >> 4;

  const float* Qb = Q + (size_t)b * SQ * DD;
  const float* Kb = K + (size_t)b * SK * DD;

  const int srow = tid >> 3;        // 0..31
  const int scol = (tid & 7) * 4;   // 0,4,...,28

  const float* qbase = Qb + (size_t)(m0 + srow) * DD + scol;
  const float* kbase = Kb + (size_t)(n0 + srow) * DD + scol;

  f32x4 acc[4][4];
#pragma unroll
  for (int i = 0; i < 4; i++)
#pragma unroll
    for (int j = 0; j < 4; j++) acc[i][j] = (f32x4){0.f, 0.f, 0.f, 0.f};

  float kss[4] = {0.f, 0.f, 0.f, 0.f};

  float4 pq[4], pk[4];
#pragma unroll
  for (int i = 0; i < 4; i++) {
    pq[i] = *(const float4*)(qbase + (size_t)i * 32 * DD);
    pk[i] = *(const float4*)(kbase + (size_t)i * 32 * DD);
  }

  for (int k0 = 0; k0 < DD; k0 += BK) {
    __syncthreads();  // previous iteration's LDS reads complete
    // ---- convert + LDS store (consumes prefetch regs)
#pragma unroll
    for (int i = 0; i < 4; i++) {
      const int r = srow + i * 32;
      float4 qv = pq[i], kv = pk[i];
      bf16_t q0 = (bf16_t)qv.x, q1 = (bf16_t)qv.y, q2 = (bf16_t)qv.z, q3 = (bf16_t)qv.w;
      bf16x4 qhv = {q0, q1, q2, q3};
      bf16x4 qlv = {(bf16_t)(qv.x - (float)q0), (bf16_t)(qv.y - (float)q1),
                    (bf16_t)(qv.z - (float)q2), (bf16_t)(qv.w - (float)q3)};
      bf16_t c0 = (bf16_t)kv.x, c1 = (bf16_t)kv.y, c2 = (bf16_t)kv.z, c3 = (bf16_t)kv.w;
      bf16x4 khv = {c0, c1, c2, c3};
      bf16x4 klv = {(bf16_t)(kv.x - (float)c0), (bf16_t)(kv.y - (float)c1),
                    (bf16_t)(kv.z - (float)c2), (bf16_t)(kv.w - (float)c3)};
      *(bf16x4*)&qh[r][scol] = qhv;
      *(bf16x4*)&ql[r][scol] = qlv;
      *(bf16x4*)&kh[r][scol] = khv;
      *(bf16x4*)&kl[r][scol] = klv;
      kss[i] = fmaf(kv.x, kv.x, kss[i]);
      kss[i] = fmaf(kv.y, kv.y, kss[i]);
      kss[i] = fmaf(kv.z, kv.z, kss[i]);
      kss[i] = fmaf(kv.w, kv.w, kss[i]);
    }
    __syncthreads();

    // ---- prefetch next tile (global reads only; hide under MFMA)
    if (k0 + BK < DD) {
#pragma unroll
      for (int i = 0; i < 4; i++) {
        pq[i] = *(const float4*)(qbase + (size_t)i * 32 * DD + (k0 + BK));
        pk[i] = *(const float4*)(kbase + (size_t)i * 32 * DD + (k0 + BK));
      }
    }

    // ---- MFMA phase
    bf16x8 bh[4], bl[4];
#pragma unroll
    for (int ni = 0; ni < 4; ni++) {
      bh[ni] = *(const bf16x8*)&kh[wn + ni * 16 + lrow][quad * 8];
      bl[ni] = *(const bf16x8*)&kl[wn + ni * 16 + lrow][quad * 8];
    }
#pragma unroll
    for (int mi = 0; mi < 4; mi++) {
      bf16x8 ah = *(const bf16x8*)&qh[wm + mi * 16 + lrow][quad * 8];
      bf16x8 al = *(const bf16x8*)&ql[wm + mi * 16 + lrow][quad * 8];
#pragma unroll
      for (int ni = 0; ni < 4; ni++) {
        acc[mi][ni] = __builtin_amdgcn_mfma_f32_16x16x32_bf16(ah, bh[ni], acc[mi][ni], 0, 0, 0);
        acc[mi][ni] = __builtin_amdgcn_mfma_f32_16x16x32_bf16(ah, bl[ni], acc[mi][ni], 0, 0, 0);
        acc[mi][ni] = __builtin_amdgcn_mfma_f32_16x16x32_bf16(al, bh[ni], acc[mi][ni], 0, 0, 0);
      }
    }
  }

  // ---- k^2 reduction (separate LDS buffer)
#pragma unroll
  for (int i = 0; i < 4; i++) ksred[srow + i * 32][tid & 7] = kss[i];
  __syncthreads();

  const float invT = 1.0f / tempP[0];
  float* Lb = logits + (size_t)b * SQ * SK;
#pragma unroll
  for (int ni = 0; ni < 4; ni++) {
    const int nl = wn + ni * 16 + lrow;
    const int n = n0 + nl;
    const float* kr = ksred[nl];
    const float ks = ((kr[0] + kr[1]) + (kr[2] + kr[3])) +
                     ((kr[4] + kr[5]) + (kr[6] + kr[7]));
#pragma unroll
    for (int mi = 0; mi < 4; mi++) {
      const int mbase = m0 + wm + mi * 16 + quad * 4;
#pragma unroll
      for (int r = 0; r < 4; r++) {
        float s = (2.0f * acc[mi][ni][r] - ks) * invT;
        Lb[(size_t)(mbase + r) * SK + n] = s;
      }
    }
  }
}

// ----------------------------------------------- row softmax (in place)
__global__ __launch_bounds__(256) void softmax_kernel(float* __restrict__ L) {
  float* p = L + (size_t)blockIdx.x * SK;
  const int tid = threadIdx.x;
  const int wave = tid >> 6, lane = tid & 63;

  float4 a = *(const float4*)(p + tid * 4);
  float4 bv = *(const float4*)(p + 1024 + tid * 4);

  float m = fmaxf(fmaxf(fmaxf(a.x, a.y), fmaxf(a.z, a.w)),
                  fmaxf(fmaxf(bv.x, bv.y), fmaxf(bv.z, bv.w)));
#pragma unroll
  for (int off = 32; off; off >>= 1) m = fmaxf(m, __shfl_xor(m, off));
  __shared__ float redm[4];
  if (lane == 0) redm[wave] = m;
  __syncthreads();
  m = fmaxf(fmaxf(redm[0], redm[1]), fmaxf(redm[2], redm[3]));

  float e[8];
  e[0] = __expf(a.x - m);  e[1] = __expf(a.y - m);
  e[2] = __expf(a.z - m);  e[3] = __expf(a.w - m);
  e[4] = __expf(bv.x - m); e[5] = __expf(bv.y - m);
  e[6] = __expf(bv.z - m); e[7] = __expf(bv.w - m);
  float s = ((e[0] + e[1]) + (e[2] + e[3])) + ((e[4] + e[5]) + (e[6] + e[7]));
#pragma unroll
  for (int off = 32; off; off >>= 1) s += __shfl_xor(s, off);
  __shared__ float reds[4];
  if (lane == 0) reds[wave] = s;
  __syncthreads();
  s = (reds[0] + reds[1]) + (reds[2] + reds[3]);

  const float inv = 1.0f / s;
  float4 oa = {e[0] * inv, e[1] * inv, e[2] * inv, e[3] * inv};
  float4 ob = {e[4] * inv, e[5] * inv, e[6] * inv, e[7] * inv};
  *(float4*)(p + tid * 4) = oa;
  *(float4*)(p + 1024 + tid * 4) = ob;
}

// ------------------------------------------------- O = W @ V (bf16 MFMA)
// V staged via register repack: thread owns (kpair p, d-chunk c); packs
// (V[2p][d],V[2p+1][d]) into one b32 LDS word. Per store instruction banks
// = (16c+p) mod 32 -> exactly 2-way (free), replacing 32-way scalar scatter.
__global__ __launch_bounds__(256, 2) void pv_kernel(const float* __restrict__ W,
                                                    const float* __restrict__ V,
                                                    float* __restrict__ O) {
  __shared__ bf16_t wt[BM][LDK];  // [m][k]
  __shared__ bf16_t vt[BN][LDK];  // [d][k]
  const int b = blockIdx.z;
  const int m0 = blockIdx.y * BM;
  const int d0 = blockIdx.x * BN;
  const int tid = threadIdx.x;
  const int lane = tid & 63;
  const int wave = tid >> 6;
  const int wm = (wave >> 1) * 64;
  const int wn = (wave & 1) * 64;
  const int lrow = lane & 15;
  const int quad = lane >> 4;

  const float* Wb = W + (size_t)b * SQ * SK;
  const float* Vb = V + (size_t)b * SK * DD;

  const int srow = tid >> 3;
  const int scol = (tid & 7) * 4;
  const int p = tid & 15;   // kpair: handles k = 2p, 2p+1
  const int c = tid >> 4;   // 0..15: d-chunks 4c and 4c+64

  const float* wbase = Wb + (size_t)(m0 + srow) * SK + scol;
  const float* vbase = Vb + (size_t)(2 * p) * DD + d0 + 4 * c;

  f32x4 acc[4][4];
#pragma unroll
  for (int i = 0; i < 4; i++)
#pragma unroll
    for (int j = 0; j < 4; j++) acc[i][j] = (f32x4){0.f, 0.f, 0.f, 0.f};

  float4 pw[4];
  float4 v0a, v1a, v0b, v1b;
#pragma unroll
  for (int i = 0; i < 4; i++) pw[i] = *(const float4*)(wbase + (size_t)i * 32 * SK);
  v0a = *(const float4*)(vbase);
  v1a = *(const float4*)(vbase + DD);
  v0b = *(const float4*)(vbase + 64);
  v1b = *(const float4*)(vbase + 64 + DD);

  for (int k0 = 0; k0 < SK; k0 += BK) {
    __syncthreads();  // previous iteration's LDS reads complete
    // ---- convert + LDS store
#pragma unroll
    for (int i = 0; i < 4; i++) {
      float4 w = pw[i];
      bf16x4 w4 = {(bf16_t)w.x, (bf16_t)w.y, (bf16_t)w.z, (bf16_t)w.w};
      *(bf16x4*)&wt[srow + i * 32][scol] = w4;
    }
    {
      bf16x2 t0 = {(bf16_t)v0a.x, (bf16_t)v1a.x};
      bf16x2 t1 = {(bf16_t)v0a.y, (bf16_t)v1a.y};
      bf16x2 t2 = {(bf16_t)v0a.z, (bf16_t)v1a.z};
      bf16x2 t3 = {(bf16_t)v0a.w, (bf16_t)v1a.w};
      *(bf16x2*)&vt[4 * c + 0][2 * p] = t0;
      *(bf16x2*)&vt[4 * c + 1][2 * p] = t1;
      *(bf16x2*)&vt[4 * c + 2][2 * p] = t2;
      *(bf16x2*)&vt[4 * c + 3][2 * p] = t3;
      bf16x2 u0 = {(bf16_t)v0b.x, (bf16_t)v1b.x};
      bf16x2 u1 = {(bf16_t)v0b.y, (bf16_t)v1b.y};
      bf16x2 u2 = {(bf16_t)v0b.z, (bf16_t)v1b.z};
      bf16x2 u3 = {(bf16_t)v0b.w, (bf16_t)v1b.w};
      *(bf16x2*)&vt[4 * c + 64 + 0][2 * p] = u0;
      *(bf16x2*)&vt[4 * c + 64 + 1][2 * p] = u1;
      *(bf16x2*)&vt[4 * c + 64 + 2][2 * p] = u2;
      *(bf16x2*)&vt[4 * c + 64 + 3][2 * p] = u3;
    }
    __syncthreads();

    // ---- prefetch next tile (global reads only)
    if (k0 + BK < SK) {
#pragma unroll
      for (int i = 0; i < 4; i++)
        pw[i] = *(const float4*)(wbase + (size_t)i * 32 * SK + (k0 + BK));
      const float* vb = vbase + (size_t)(k0 + BK) * DD;
      v0a = *(const float4*)(vb);
      v1a = *(const float4*)(vb + DD);
      v0b = *(const float4*)(vb + 64);
      v1b = *(const float4*)(vb + 64 + DD);
    }

    // ---- MFMA phase
    bf16x8 a[4], bb[4];
#pragma unroll
    for (int mi = 0; mi < 4; mi++)
      a[mi] = *(const bf16x8*)&wt[wm + mi * 16 + lrow][quad * 8];
#pragma unroll
    for (int ni = 0; ni < 4; ni++)
      bb[ni] = *(const bf16x8*)&vt[wn + ni * 16 + lrow][quad * 8];
#pragma unroll
    for (int mi = 0; mi < 4; mi++)
#pragma unroll
      for (int ni = 0; ni < 4; ni++)
        acc[mi][ni] = __builtin_amdgcn_mfma_f32_16x16x32_bf16(a[mi], bb[ni], acc[mi][ni], 0, 0, 0);
  }

  float* Ob = O + (size_t)b * SQ * DD;
#pragma unroll
  for (int ni = 0; ni < 4; ni++) {
    const int d = d0 + wn + ni * 16 + lrow;
#pragma unroll
    for (int mi = 0; mi < 4; mi++) {
      const int mbase = m0 + wm + mi * 16 + quad * 4;
#pragma unroll
      for (int r = 0; r < 4; r++) {
        Ob[(size_t)(mbase + r) * DD + d] = acc[mi][ni][r];
      }
    }
  }
}

extern "C" void kernel_launch(void* const* d_in, const int* in_sizes, int n_in,
                              void* d_out, int out_size, void* d_ws, size_t ws_size,
                              hipStream_t stream) {
  const float* Q = (const float*)d_in[0];
  const float* K = (const float*)d_in[1];
  const float* V = (const float*)d_in[2];
  const float* T = (const float*)d_in[3];

  float* outv = (float*)d_out;                          // [8,2048,512]
  float* logits = outv + (size_t)NB * SQ * DD;          // [8,2048,2048] (weights region)

  logits_kernel<<<dim3(SK / BN, SQ / BM, NB), 256, 0, stream>>>(Q, K, T, logits);
  softmax_kernel<<<NB * SQ, 256, 0, stream>>>(logits);
  pv_kernel<<<dim3(DD / BN, SQ / BM, NB), 256, 0, stream>>>(logits, V, outv);
}